// Round 17
// baseline (304.101 us; speedup 1.0000x reference)
//
#include <hip/hip_runtime.h>

typedef _Float16 f16;
typedef _Float16 half4 __attribute__((ext_vector_type(4)));
typedef _Float16 half8 __attribute__((ext_vector_type(8)));
typedef float f32x4 __attribute__((ext_vector_type(4)));

#define BATCH 4

// async global -> LDS, 16B per lane; dest = wave-uniform base + lane*16
__device__ __forceinline__ void gload16(const void* g, void* l) {
  __builtin_amdgcn_global_load_lds((const __attribute__((address_space(1))) unsigned int*)g,
                                   (__attribute__((address_space(3))) unsigned int*)l, 16, 0, 0);
}

template<int N> __device__ __forceinline__ void wait_vmcnt() {
  static_assert(N == 0 || N == 6, "add literal");
  if constexpr (N == 0)      asm volatile("s_waitcnt vmcnt(0)" ::: "memory");
  else if constexpr (N == 6) asm volatile("s_waitcnt vmcnt(6)" ::: "memory");
}

// ===================== border-zero helper =====================
template<int DP, int ROWB>
__device__ __forceinline__ void zb_one(char* __restrict__ buf, int v, int b) {
  int w = v % DP; int t = v / DP; int h = t % DP; int d = t / DP;
  bool border = (w == 0) | (w == DP - 1) | (h == 0) | (h == DP - 1) | (d == 0) | (d == DP - 1);
  if (!border) return;
  char* p = buf + ((size_t)b * DP * DP * DP + v) * ROWB;
  #pragma unroll
  for (int i = 0; i < ROWB; i += 8)
    *reinterpret_cast<unsigned long long*>(p + i) = 0ull;
}

// ===================== merged weight prep (1 launch) =====================
__global__ __launch_bounds__(256) void wprep_all_k(const float* __restrict__ w1,
                                                   const float* __restrict__ w2,
                                                   const float* __restrict__ w3,
                                                   const float* __restrict__ w4,
                                                   f16* __restrict__ wf1,
                                                   f16* __restrict__ wf2,
                                                   f16* __restrict__ wf3,
                                                   f16* __restrict__ wf4) {
  const int T1 = 64 * 128;
  const int T2 = 27 * 128 * 64;
  const int T3 = 27 * 256 * 128;
  const int T4 = 27 * 512 * 256;
  int idx = blockIdx.x * 256 + threadIdx.x;
  if (idx < T1) {
    int q = idx & 127, co = idx >> 7;
    int k = q >> 2, ci = q & 3;
    float v = (ci < 3 && k < 27) ? w1[(co * 3 + ci) * 27 + k] : 0.f;
    wf1[idx] = (f16)v;
    return;
  }
  idx -= T1;
  const float* w; f16* wo; int COUT, CIN;
  if (idx < T2)       { w = w2; wo = wf2; COUT = 128; CIN = 64; }
  else if ((idx -= T2) < T3) { w = w3; wo = wf3; COUT = 256; CIN = 128; }
  else if ((idx -= T3) < T4) { w = w4; wo = wf4; COUT = 512; CIN = 256; }
  else return;
  int k = idx % 27;
  int t = idx / 27;
  int ci = t % CIN;
  int co = t / CIN;
  wo[((size_t)k * COUT + co) * CIN + ci] = (f16)w[idx];
}

// ===================== merged pre-conv1 prep: xcp fill + h1p/h2p/h3p border zero =====================
__global__ __launch_bounds__(256) void prep_all_k(const float* __restrict__ x,
                                                  const int* __restrict__ mask,
                                                  f16* __restrict__ xcp,
                                                  char* __restrict__ h1p,
                                                  char* __restrict__ h2p,
                                                  char* __restrict__ h3p) {
  const int D3 = 262144, PD = 66, PD3 = PD * PD * PD;
  const int N3 = 34 * 34 * 34, N4 = 18 * 18 * 18;
  int idx = blockIdx.x * 256 + threadIdx.x;
  int b = blockIdx.y;
  if (idx < PD3) {
    int pv = idx;
    int pw = pv % PD; int t = pv / PD; int ph = t % PD; int pd = t / PD;
    half4 o = {};
    if (pw > 0 && pw < 65 && ph > 0 && ph < 65 && pd > 0 && pd < 65) {
      int v = (((pd - 1) * 64) + (ph - 1)) * 64 + (pw - 1);
      if (mask[(size_t)b * D3 + v] < 1) {
        const float* xb = x + (size_t)b * 3 * D3 + v;
        o[0] = (f16)xb[0];
        o[1] = (f16)xb[D3];
        o[2] = (f16)xb[2 * D3];
      }
    }
    *reinterpret_cast<half4*>(xcp + ((size_t)b * PD3 + pv) * 4) = o;
    return;
  }
  idx -= PD3;
  if (idx < PD3) { zb_one<66, 128>(h1p, idx, b); return; }
  idx -= PD3;
  if (idx < N3) { zb_one<34, 256>(h2p, idx, b); return; }
  idx -= N3;
  if (idx < N4) zb_one<18, 512>(h3p, idx, b);
}

// ===================== mask pyramid =====================
__global__ __launch_bounds__(256) void dil_w_k(const int* __restrict__ mask,
                                               unsigned char* __restrict__ aw) {
  const int D3 = 262144;
  int t = blockIdx.x * 256 + threadIdx.x;
  int b = t >> 16;
  int v = (t & 65535) * 4;
  int w0 = v & 63;
  const int* mb = mask + (size_t)b * D3;
  int a[6];
  a[0] = (w0 > 0) ? (mb[v - 1] < 1) : 0;
  #pragma unroll
  for (int i = 0; i < 4; i++) a[i + 1] = mb[v + i] < 1;
  a[5] = (w0 < 60) ? (mb[v + 4] < 1) : 0;
  unsigned int o = 0;
  #pragma unroll
  for (int i = 0; i < 4; i++)
    o |= ((unsigned)(a[i] | a[i + 1] | a[i + 2])) << (8 * i);
  *reinterpret_cast<unsigned int*>(aw + (size_t)b * D3 + v) = o;
}

// merged h+d dilation: m1 = OR over 3x3 (h,d) window of aw
__global__ __launch_bounds__(256) void dil_hd2_k(const unsigned char* __restrict__ aw,
                                                 unsigned char* __restrict__ m1) {
  const int D3 = 262144;
  int t = blockIdx.x * 256 + threadIdx.x;
  int b = t >> 16;
  int v = (t & 65535) * 4;
  int h = (v >> 6) & 63;
  int d = v >> 12;
  const unsigned char* ib = aw + (size_t)b * D3;
  unsigned int m = 0;
  #pragma unroll
  for (int dd = -1; dd <= 1; dd++) {
    int id = d + dd; if ((unsigned)id >= 64u) continue;
    #pragma unroll
    for (int hh = -1; hh <= 1; hh++) {
      int ih = h + hh; if ((unsigned)ih >= 64u) continue;
      m |= *reinterpret_cast<const unsigned int*>(ib + ((id << 12) | (ih << 6) | (v & 63)));
    }
  }
  *reinterpret_cast<unsigned int*>(m1 + (size_t)b * D3 + v) = m;
}

// m2/m3/m4 direct from m1 (windows 3/7/15 at strides 2/4/8) + zero d_out, one launch.
__global__ __launch_bounds__(256) void dil_rest_k(const unsigned char* __restrict__ m1,
                                                  unsigned char* __restrict__ m2,
                                                  unsigned char* __restrict__ m3,
                                                  unsigned char* __restrict__ m4,
                                                  float* __restrict__ outp) {
  const int D = 64, D3 = 262144;
  const int S2 = BATCH * 32768, S3 = BATCH * 4096, S4 = BATCH * 512;
  int idx = blockIdx.x * 256 + threadIdx.x;
  int b, v, LOGD, H, ST;
  unsigned char* mo;
  if (idx < S2)                 { b = idx >> 15; v = idx & 32767; LOGD = 5; H = 1; ST = 2; mo = m2 + (size_t)b * 32768; }
  else if ((idx -= S2) < S3)    { b = idx >> 12; v = idx & 4095;  LOGD = 4; H = 3; ST = 4; mo = m3 + (size_t)b * 4096; }
  else if ((idx -= S3) < S4)    { b = idx >> 9;  v = idx & 511;   LOGD = 3; H = 7; ST = 8; mo = m4 + (size_t)b * 512; }
  else if ((idx -= S4) < 2048)  { outp[idx] = 0.f; return; }
  else return;
  int DM = (1 << LOGD) - 1;
  int ow = v & DM, oh = (v >> LOGD) & DM, od = v >> (2 * LOGD);
  const unsigned char* mb = m1 + (size_t)b * D3;
  int act = 0;
  for (int dd = -H; dd <= H && !act; dd++) {
    int id = od * ST + dd; if ((unsigned)id >= (unsigned)D) continue;
    for (int hh = -H; hh <= H && !act; hh++) {
      int ih = oh * ST + hh; if ((unsigned)ih >= (unsigned)D) continue;
      for (int ww = -H; ww <= H; ww++) {
        int iw = ow * ST + ww; if ((unsigned)iw >= (unsigned)D) continue;
        if (mb[((size_t)id * D + ih) * D + iw]) { act = 1; break; }
      }
    }
  }
  mo[v] = (unsigned char)act;
}

// ===================== conv1 via MFMA — halo-tile staging (R16-proven) =====================
template<int BM>
__global__ __launch_bounds__(256) void conv1_mfma_k(const f16* __restrict__ xcp,
                                                    const f16* __restrict__ w1f,
                                                    const float* __restrict__ bias,
                                                    const unsigned char* __restrict__ mo,
                                                    f16* __restrict__ out /* h1p padded */) {
  const int D3 = 262144, COUT = 64, PD = 66, PD3 = PD * PD * PD;
  constexpr int K = 128, LDB = K + 8;
  constexpr int WM = 2, WN = 2;
  constexpr int MF = BM / (16 * WM), NF = 64 / (16 * WN);
  __shared__ __align__(16) f16 halo[1056 * 4];
  __shared__ __align__(16) f16 Bs[64][LDB];

  const int tid = threadIdx.x, lane = tid & 63, wave = tid >> 6;
  const int wm = wave >> 1, wn = wave & 1;
  const int v0 = blockIdx.x * BM;
  const int b = blockIdx.y;
  const int oh0 = (v0 >> 6) & 63, od = v0 >> 12;
  const f16* xb = xcp + (size_t)b * PD3 * 4;

  for (int c = tid; c < 64 * (K / 8); c += 256) {
    int row = c >> 4, cc = c & 15;
    *reinterpret_cast<half8*>(&Bs[row][cc * 8]) =
        *reinterpret_cast<const half8*>(w1f + row * K + cc * 8);
  }
  for (int e = tid; e < 1056; e += 256) {
    half4 val = {};
    if (e < 792) {
      int d = e / 264, r = e - d * 264, h = r / 66, w = r - h * 66;
      val = *reinterpret_cast<const half4*>(
          xb + (((size_t)(od + d) * PD + (oh0 + h)) * PD + w) * 4);
    }
    *reinterpret_cast<half4*>(&halo[(size_t)e * 4]) = val;
  }
  __syncthreads();

  const int ll = lane & 15, lh = lane >> 4;
  int koff[8];
  #pragma unroll
  for (int i = 0; i < 8; i++) {
    int ks = (i >> 1) * 8 + 2 * lh + (i & 1);
    int kd = ks / 9, rr = ks - kd * 9, kh = rr / 3, kw = rr - kh * 3;
    koff[i] = ((kd * 4 + kh) * 66 + kw) * 4;
  }
  const int lbase = (wm * 66 + ll) * 4;

  f32x4 acc[MF][NF] = {};
  #pragma unroll
  for (int q = 0; q < 4; q++) {
    half8 a[MF], bb[NF];
    #pragma unroll
    for (int mf = 0; mf < MF; mf++) {
      half4 lo = *reinterpret_cast<const half4*>(&halo[lbase + mf * 64 + koff[q * 2]]);
      half4 hi = *reinterpret_cast<const half4*>(&halo[lbase + mf * 64 + koff[q * 2 + 1]]);
      a[mf] = half8{lo[0], lo[1], lo[2], lo[3], hi[0], hi[1], hi[2], hi[3]};
    }
    #pragma unroll
    for (int nf = 0; nf < NF; nf++)
      bb[nf] = *reinterpret_cast<const half8*>(&Bs[wn * NF * 16 + nf * 16 + ll][q * 32 + lh * 8]);
    #pragma unroll
    for (int mf = 0; mf < MF; mf++)
      #pragma unroll
      for (int nf = 0; nf < NF; nf++)
        acc[mf][nf] = __builtin_amdgcn_mfma_f32_16x16x32_f16(a[mf], bb[nf], acc[mf][nf], 0, 0, 0);
  }

  const unsigned char* mb = mo + (size_t)b * D3;
  f16* ob = out + (size_t)b * PD3 * COUT;
  float bv[NF];
  #pragma unroll
  for (int nf = 0; nf < NF; nf++) bv[nf] = bias[wn * NF * 16 + nf * 16 + ll];
  #pragma unroll
  for (int mf = 0; mf < MF; mf++) {
    #pragma unroll
    for (int r = 0; r < 4; r++) {
      int v = v0 + wm * MF * 16 + mf * 16 + (lh << 2) + r;
      bool act = mb[v] != 0;
      int ow = v & 63, oh = (v >> 6) & 63, odv = v >> 12;
      size_t pv = ((size_t)(odv + 1) * PD + oh + 1) * PD + ow + 1;
      #pragma unroll
      for (int nf = 0; nf < NF; nf++) {
        int co = wn * NF * 16 + nf * 16 + ll;
        float val = acc[mf][nf][r] + bv[nf];
        val = act ? (val > 0.f ? val : 0.f) : 0.f;
        ob[pv * COUT + co] = (f16)val;
      }
    }
  }
}

// ===================== conv2: NBUF=3 ring, depth-2 counted vmcnt, 2 blocks/CU =====================
// Per step: wait vmcnt(L) [tap s done, tap s+1 stays in flight] -> s_barrier ->
// issue stage(s+2) -> MFMA on buf[s%3]. LDS 72KB -> 2 blocks/CU (8 waves/CU TLP kept).
template<int CIN, int COUT, int DIN, int DOUT, int BM, int BN, int WM, int WN, int SWZ>
__global__ __launch_bounds__(WM * WN * 64) void conv_p3_k(const f16* __restrict__ in,
                                                          const f16* __restrict__ w27,
                                                          const float* __restrict__ bias,
                                                          const unsigned char* __restrict__ mo,
                                                          f16* __restrict__ out) {
  constexpr int PD = DIN + 2, PDo = DOUT + 2;
  constexpr int NW = WM * WN;
  constexpr int MF = BM / (16 * WM), NF = BN / (16 * WN);
  constexpr int ROWB = CIN * 2;
  constexpr int CHUNKS = ROWB / 16;      // 8
  constexpr int RPI = 64 / CHUNKS;       // 8
  constexpr int A_IW = BM / RPI / NW;    // 2
  constexpr int B_IW = BN / RPI / NW;    // 4
  constexpr int L = A_IW + B_IW;         // 6
  constexpr int CI0S = CIN / 32;
  constexpr int D3o = DOUT * DOUT * DOUT;
  constexpr int LOGD = 5;                // DOUT == 32

  __shared__ __align__(16) char As[3][BM * ROWB];
  __shared__ __align__(16) char Bs[3][BN * ROWB];

  const int tid = threadIdx.x, lane = tid & 63, wave = tid >> 6;
  const int wm = wave / WN, wn = wave % WN;
  int bx = blockIdx.x;
  if (SWZ) {
    int cpx = gridDim.x >> 3;
    bx = (bx & 7) * cpx + (bx >> 3);
  }
  const int v0 = bx * BM, co0 = blockIdx.y * BN, bz = blockIdx.z;

  const int lrow = lane / CHUNKS;
  const int lchunk = lane % CHUNKS;
  const char* a_src[A_IW];
  #pragma unroll
  for (int i = 0; i < A_IW; i++) {
    int r = (wave * A_IW + i) * RPI + lrow;
    int v = v0 + r;
    int ow = v & (DOUT - 1), oh = (v >> LOGD) & (DOUT - 1), od = v >> (2 * LOGD);
    size_t flat = (size_t)bz * PD * PD * PD + ((size_t)(2 * od) * PD + 2 * oh) * PD + 2 * ow;
    a_src[i] = (const char*)in + flat * ROWB + (lchunk ^ (r & 7)) * 16;
  }
  const char* b_src[B_IW];
  #pragma unroll
  for (int i = 0; i < B_IW; i++) {
    int r = (wave * B_IW + i) * RPI + lrow;
    b_src[i] = (const char*)w27 + (size_t)(co0 + r) * ROWB + (lchunk ^ (r & 7)) * 16;
  }

  auto stage = [&](int buf, int k) {
    int kd = k / 9, r2 = k - kd * 9, kh = r2 / 3, kw = r2 - kh * 3;
    int koff = ((kd * PD + kh) * PD + kw) * ROWB;
    #pragma unroll
    for (int i = 0; i < A_IW; i++)
      gload16(a_src[i] + koff, &As[buf][(wave * A_IW + i) * 1024]);
    size_t wko = (size_t)k * COUT * ROWB;
    #pragma unroll
    for (int i = 0; i < B_IW; i++)
      gload16(b_src[i] + wko, &Bs[buf][(wave * B_IW + i) * 1024]);
  };

  f32x4 acc[MF][NF] = {};
  const int ll = lane & 15, lh = lane >> 4;
  const int ra0 = wm * MF * 16 + ll;
  const int rb0 = wn * NF * 16 + ll;
  const int rswa = ra0 & 7;
  const int rswb = rb0 & 7;

  stage(0, 0);
  stage(1, 1);
  int cur = 0;
  for (int s = 0; s < 27; s++) {
    if (s < 26) wait_vmcnt<6>();         // tap s done; tap s+1 stays in flight
    else        wait_vmcnt<0>();
    __builtin_amdgcn_s_barrier();        // all waves' tap-s data resident
    asm volatile("" ::: "memory");
    if (s + 2 < 27) {
      int nb = cur + 2; if (nb >= 3) nb -= 3;
      stage(nb, s + 2);
    }
    #pragma unroll
    for (int c = 0; c < CI0S; c++) {
      const int q = c * 4 + lh;
      half8 a[MF], bb[NF];
      #pragma unroll
      for (int mf = 0; mf < MF; mf++)
        a[mf] = *reinterpret_cast<const half8*>(
            &As[cur][(ra0 + mf * 16) * ROWB + ((q ^ rswa) * 16)]);
      #pragma unroll
      for (int nf = 0; nf < NF; nf++)
        bb[nf] = *reinterpret_cast<const half8*>(
            &Bs[cur][(rb0 + nf * 16) * ROWB + ((q ^ rswb) * 16)]);
      #pragma unroll
      for (int mf = 0; mf < MF; mf++)
        #pragma unroll
        for (int nf = 0; nf < NF; nf++)
          acc[mf][nf] = __builtin_amdgcn_mfma_f32_16x16x32_f16(a[mf], bb[nf], acc[mf][nf], 0, 0, 0);
    }
    asm volatile("" ::: "memory");
    cur = (cur + 1 == 3) ? 0 : cur + 1;
  }

  // ---- epilogue (padded output) ----
  f16* ob = out;
  float bv[NF];
  #pragma unroll
  for (int nf = 0; nf < NF; nf++) bv[nf] = bias[co0 + wn * NF * 16 + nf * 16 + ll];
  #pragma unroll
  for (int mf = 0; mf < MF; mf++) {
    #pragma unroll
    for (int r = 0; r < 4; r++) {
      int v = v0 + wm * MF * 16 + mf * 16 + (lh << 2) + r;
      bool act = mo[(size_t)bz * D3o + v] != 0;
      int ow = v & (DOUT - 1), oh = (v >> LOGD) & (DOUT - 1), od = v >> (2 * LOGD);
      size_t pv = ((size_t)(od + 1) * PDo + oh + 1) * PDo + ow + 1;
      size_t obase = ((size_t)bz * PDo * PDo * PDo + pv) * COUT;
      #pragma unroll
      for (int nf = 0; nf < NF; nf++) {
        int co = co0 + wn * NF * 16 + nf * 16 + ll;
        float val = acc[mf][nf][r] + bv[nf];
        val = act ? (val > 0.f ? val : 0.f) : 0.f;
        ob[obase + co] = (f16)val;
      }
    }
  }
}

// ===================== stride-2 conv, 2-phase dbuf MFMA (conv3/conv4, R11-proven) =====================
template<int CINS, int CINF, int COUT, int DIN, int DOUT, int BM, int BN,
         int WM, int WN, int SWZ, int OP, int BMERGE, int POOL>
__global__ __launch_bounds__(WM * WN * 64) void conv_mfma2_k(const f16* __restrict__ in,
                                                             const f16* __restrict__ w27,
                                                             const float* __restrict__ bias,
                                                             const unsigned char* __restrict__ mo,
                                                             f16* __restrict__ out,
                                                             float* __restrict__ poolp) {
  constexpr int PD = DIN + 2, PDo = DOUT + 2;
  constexpr int NW = WM * WN;
  constexpr int MF = BM / (16 * WM), NF = BN / (16 * WN);
  constexpr int ROWB = CINS * 2;
  constexpr int ROWBF = CINF * 2;
  constexpr int CHUNKS = ROWB / 16;
  constexpr int RPI = 64 / CHUNKS;
  constexpr int A_IW = BM / RPI / NW;
  constexpr int B_IW = BN / RPI / NW;
  constexpr int CIH = CINF / CINS;
  constexpr int NSTEP = 27 * CIH;
  constexpr int CI0S = CINS / 32;
  constexpr int D3o = DOUT * DOUT * DOUT;
  constexpr int LOGD = (DOUT == 32) ? 5 : ((DOUT == 16) ? 4 : 3);

  __shared__ __align__(16) char As[2][BM * ROWB];
  __shared__ __align__(16) char Bs[2][BN * ROWB];

  const int tid = threadIdx.x, lane = tid & 63, wave = tid >> 6;
  const int wm = wave / WN, wn = wave % WN;
  int bx = blockIdx.x;
  if (SWZ) {
    int cpx = gridDim.x >> 3;
    bx = (bx & 7) * cpx + (bx >> 3);
  }
  const int v0 = bx * BM, co0 = blockIdx.y * BN;
  const int bz = BMERGE ? 0 : blockIdx.z;

  auto key = [](int r) -> int { return (CHUNKS >= 8) ? (r & 7) : ((r >> 1) & 3); };

  const int lrow = lane / CHUNKS;
  const int lchunk = lane % CHUNKS;
  const char* a_src[A_IW];
  #pragma unroll
  for (int i = 0; i < A_IW; i++) {
    int r = (wave * A_IW + i) * RPI + lrow;
    int v = v0 + r;
    int vb = BMERGE ? (v >> (3 * LOGD)) : bz;
    int vv = BMERGE ? (v & (D3o - 1)) : v;
    int ow = vv & (DOUT - 1), oh = (vv >> LOGD) & (DOUT - 1), od = vv >> (2 * LOGD);
    size_t flat = (size_t)vb * PD * PD * PD + ((size_t)(2 * od) * PD + 2 * oh) * PD + 2 * ow;
    a_src[i] = (const char*)in + flat * ROWBF + (lchunk ^ key(r)) * 16;
  }
  const char* b_src[B_IW];
  #pragma unroll
  for (int i = 0; i < B_IW; i++) {
    int r = (wave * B_IW + i) * RPI + lrow;
    b_src[i] = (const char*)w27 + (size_t)(co0 + r) * ROWBF + (lchunk ^ key(r)) * 16;
  }

  auto stage = [&](int buf, int s) {
    int k = s / CIH;
    int h = s - k * CIH;
    int kd = k / 9, r2 = k - kd * 9, kh = r2 / 3, kw = r2 - kh * 3;
    int koff = ((kd * PD + kh) * PD + kw) * ROWBF + h * ROWB;
    #pragma unroll
    for (int i = 0; i < A_IW; i++)
      gload16(a_src[i] + koff, &As[buf][(wave * A_IW + i) * 1024]);
    size_t wko = (size_t)k * COUT * ROWBF + h * ROWB;
    #pragma unroll
    for (int i = 0; i < B_IW; i++)
      gload16(b_src[i] + wko, &Bs[buf][(wave * B_IW + i) * 1024]);
  };

  f32x4 acc[MF][NF] = {};
  const int ll = lane & 15, lh = lane >> 4;
  const int ra0 = wm * MF * 16 + ll;
  const int rb0 = wn * NF * 16 + ll;
  const int rswa = key(ra0);
  const int rswb = key(rb0);

  stage(0, 0);
  __syncthreads();
  int cur = 0;
  for (int s = 0; s < NSTEP; s++) {
    if (s < NSTEP - 1) stage(cur ^ 1, s + 1);
    #pragma unroll
    for (int c = 0; c < CI0S; c++) {
      const int q = c * 4 + lh;
      half8 a[MF], bb[NF];
      #pragma unroll
      for (int mf = 0; mf < MF; mf++)
        a[mf] = *reinterpret_cast<const half8*>(
            &As[cur][(ra0 + mf * 16) * ROWB + ((q ^ rswa) * 16)]);
      #pragma unroll
      for (int nf = 0; nf < NF; nf++)
        bb[nf] = *reinterpret_cast<const half8*>(
            &Bs[cur][(rb0 + nf * 16) * ROWB + ((q ^ rswb) * 16)]);
      #pragma unroll
      for (int mf = 0; mf < MF; mf++)
        #pragma unroll
        for (int nf = 0; nf < NF; nf++)
          acc[mf][nf] = __builtin_amdgcn_mfma_f32_16x16x32_f16(a[mf], bb[nf], acc[mf][nf], 0, 0, 0);
    }
    __syncthreads();
    cur ^= 1;
  }

  f16* ob = out;
  float bv[NF];
  #pragma unroll
  for (int nf = 0; nf < NF; nf++) bv[nf] = bias[co0 + wn * NF * 16 + nf * 16 + ll];
  float pmax[NF];
  #pragma unroll
  for (int nf = 0; nf < NF; nf++) pmax[nf] = 0.f;
  #pragma unroll
  for (int mf = 0; mf < MF; mf++) {
    #pragma unroll
    for (int r = 0; r < 4; r++) {
      int v = v0 + wm * MF * 16 + mf * 16 + (lh << 2) + r;
      int vb = BMERGE ? (v >> (3 * LOGD)) : bz;
      int vv = BMERGE ? (v & (D3o - 1)) : v;
      bool act = mo[(size_t)vb * D3o + vv] != 0;
      int ow = vv & (DOUT - 1), oh = (vv >> LOGD) & (DOUT - 1), od = vv >> (2 * LOGD);
      size_t pv = OP ? (((size_t)(od + 1) * PDo + oh + 1) * PDo + ow + 1) : (size_t)vv;
      size_t obase = ((size_t)vb * (OP ? PDo * PDo * PDo : D3o) + pv) * COUT;
      #pragma unroll
      for (int nf = 0; nf < NF; nf++) {
        int co = co0 + wn * NF * 16 + nf * 16 + ll;
        float val = acc[mf][nf][r] + bv[nf];
        val = act ? (val > 0.f ? val : 0.f) : 0.f;
        if constexpr (POOL) {
          pmax[nf] = fmaxf(pmax[nf], val);
        } else {
          ob[obase + co] = (f16)val;
        }
      }
    }
  }
  if constexpr (POOL) {
    #pragma unroll
    for (int nf = 0; nf < NF; nf++) {
      int co = co0 + wn * NF * 16 + nf * 16 + ll;
      atomicMax((int*)poolp + bz * 512 + co, __float_as_int(pmax[nf]));
    }
  }
}

extern "C" void kernel_launch(void* const* d_in, const int* in_sizes, int n_in,
                              void* d_out, int out_size, void* d_ws, size_t ws_size,
                              hipStream_t stream) {
  const float* x    = (const float*)d_in[0];
  const int*   mask = (const int*)d_in[1];
  const float* w1 = (const float*)d_in[2];
  const float* b1 = (const float*)d_in[3];
  const float* w2 = (const float*)d_in[4];
  const float* b2 = (const float*)d_in[5];
  const float* w3 = (const float*)d_in[6];
  const float* b3 = (const float*)d_in[7];
  const float* w4 = (const float*)d_in[8];
  const float* b4 = (const float*)d_in[9];
  float* outp = (float*)d_out;

  const size_t PD1 = 66 * 66 * 66;   // 287496
  const size_t PD2 = 34 * 34 * 34;   // 39304
  const size_t PD3s = 18 * 18 * 18;  // 5832

  char* ws = (char*)d_ws;
  size_t off = 0;
  auto alloc = [&](size_t bytes) -> char* {
    char* p = ws + off;
    off = (off + bytes + 255) & ~(size_t)255;
    return p;
  };
  f16* wf1 = (f16*)alloc((size_t)64 * 128 * 2);
  f16* wf2 = (f16*)alloc((size_t)27 * 128 * 64 * 2);
  f16* wf3 = (f16*)alloc((size_t)27 * 256 * 128 * 2);
  f16* wf4 = (f16*)alloc((size_t)27 * 512 * 256 * 2);
  unsigned char* aw = (unsigned char*)alloc((size_t)BATCH * 262144);
  unsigned char* m1 = (unsigned char*)alloc((size_t)BATCH * 262144);
  unsigned char* m2 = (unsigned char*)alloc((size_t)BATCH * 32768);
  unsigned char* m3 = (unsigned char*)alloc((size_t)BATCH * 4096);
  unsigned char* m4 = (unsigned char*)alloc((size_t)BATCH * 512);
  f16* h1p = (f16*)alloc((size_t)BATCH * PD1 * 64 * 2);    // 147 MB
  f16* h2p = (f16*)alloc((size_t)BATCH * PD2 * 128 * 2);   // 40 MB
  f16* h3p = (f16*)alloc((size_t)BATCH * PD3s * 256 * 2);  // 12 MB
  f16* xcp = (f16*)alloc((size_t)BATCH * PD1 * 4 * 2);     // 9.2 MB
  if (off > ws_size) return;

  // merged weight prep (1 launch)
  {
    const int TOT = 64 * 128 + 27 * 128 * 64 + 27 * 256 * 128 + 27 * 512 * 256;
    wprep_all_k<<<dim3((TOT + 255) / 256), 256, 0, stream>>>(w1, w2, w3, w4, wf1, wf2, wf3, wf4);
  }

  // mask pyramid
  dil_w_k<<<dim3(BATCH * 65536 / 256), 256, 0, stream>>>(mask, aw);
  dil_hd2_k<<<dim3(BATCH * 65536 / 256), 256, 0, stream>>>(aw, m1);
  {
    const int TOT = BATCH * 32768 + BATCH * 4096 + BATCH * 512 + 2048;
    dil_rest_k<<<dim3((TOT + 255) / 256), 256, 0, stream>>>(m1, m2, m3, m4, outp);
  }

  // merged prep: xcp fill + h1p/h2p/h3p border zero (1 launch)
  {
    const int TOT = 287496 * 2 + 39304 + 5832;
    prep_all_k<<<dim3((TOT + 255) / 256, BATCH), 256, 0, stream>>>(
        x, mask, xcp, (char*)h1p, (char*)h2p, (char*)h3p);
  }

  // conv1 (halo-tile staging)
  conv1_mfma_k<128><<<dim3(262144 / 128, BATCH), 256, 0, stream>>>(xcp, wf1, b1, m1, h1p);

  // conv2: NBUF=3 depth-2 counted-vmcnt, 72KB LDS -> 2 blocks/CU, grid 512x1x4, SWZ
  conv_p3_k<64, 128, 64, 32, 64, 128, 2, 2, 1>
      <<<dim3(512, 1, BATCH), 256, 0, stream>>>(h1p, wf2, b2, m2, h2p);
  // conv3: batch-merged M=16384, CINS64 ci-split2, BM64 BN128, 48KB, grid 256x2, SWZ
  conv_mfma2_k<64, 128, 256, 32, 16, 64, 128, 2, 2, 1, 1, 1, 0>
      <<<dim3(256, 2, 1), 256, 0, stream>>>(h2p, wf3, b3, m3, h3p, nullptr);
  // conv4: CINS128 ci-split2, BM32 BN64, 2 waves, 48KB, grid 16x8x4 — POOL fused (atomicMax)
  conv_mfma2_k<128, 256, 512, 16, 8, 32, 64, 1, 2, 0, 0, 0, 1>
      <<<dim3(16, 8, BATCH), 128, 0, stream>>>(h3p, wf4, b4, m4, nullptr, outp);
}

// Round 18
// 285.387 us; speedup vs baseline: 1.0656x; 1.0656x over previous
//
#include <hip/hip_runtime.h>

typedef _Float16 f16;
typedef _Float16 half4 __attribute__((ext_vector_type(4)));
typedef _Float16 half8 __attribute__((ext_vector_type(8)));
typedef float f32x4 __attribute__((ext_vector_type(4)));

#define BATCH 4

// async global -> LDS, 16B per lane; dest = wave-uniform base + lane*16
__device__ __forceinline__ void gload16(const void* g, void* l) {
  __builtin_amdgcn_global_load_lds((const __attribute__((address_space(1))) unsigned int*)g,
                                   (__attribute__((address_space(3))) unsigned int*)l, 16, 0, 0);
}

// ===================== border-zero helper =====================
template<int DP, int ROWB>
__device__ __forceinline__ void zb_one(char* __restrict__ buf, int v, int b) {
  int w = v % DP; int t = v / DP; int h = t % DP; int d = t / DP;
  bool border = (w == 0) | (w == DP - 1) | (h == 0) | (h == DP - 1) | (d == 0) | (d == DP - 1);
  if (!border) return;
  char* p = buf + ((size_t)b * DP * DP * DP + v) * ROWB;
  #pragma unroll
  for (int i = 0; i < ROWB; i += 8)
    *reinterpret_cast<unsigned long long*>(p + i) = 0ull;
}

// ===================== merged weight prep (1 launch) =====================
__global__ __launch_bounds__(256) void wprep_all_k(const float* __restrict__ w1,
                                                   const float* __restrict__ w2,
                                                   const float* __restrict__ w3,
                                                   const float* __restrict__ w4,
                                                   f16* __restrict__ wf1,
                                                   f16* __restrict__ wf2,
                                                   f16* __restrict__ wf3,
                                                   f16* __restrict__ wf4) {
  const int T1 = 64 * 128;
  const int T2 = 27 * 128 * 64;
  const int T3 = 27 * 256 * 128;
  const int T4 = 27 * 512 * 256;
  int idx = blockIdx.x * 256 + threadIdx.x;
  if (idx < T1) {
    int q = idx & 127, co = idx >> 7;
    int k = q >> 2, ci = q & 3;
    float v = (ci < 3 && k < 27) ? w1[(co * 3 + ci) * 27 + k] : 0.f;
    wf1[idx] = (f16)v;
    return;
  }
  idx -= T1;
  const float* w; f16* wo; int COUT, CIN;
  if (idx < T2)       { w = w2; wo = wf2; COUT = 128; CIN = 64; }
  else if ((idx -= T2) < T3) { w = w3; wo = wf3; COUT = 256; CIN = 128; }
  else if ((idx -= T3) < T4) { w = w4; wo = wf4; COUT = 512; CIN = 256; }
  else return;
  int k = idx % 27;
  int t = idx / 27;
  int ci = t % CIN;
  int co = t / CIN;
  wo[((size_t)k * COUT + co) * CIN + ci] = (f16)w[idx];
}

// ===================== merged pre-conv1 prep: xcp fill + h1p/h2p/h3p border zero =====================
__global__ __launch_bounds__(256) void prep_all_k(const float* __restrict__ x,
                                                  const int* __restrict__ mask,
                                                  f16* __restrict__ xcp,
                                                  char* __restrict__ h1p,
                                                  char* __restrict__ h2p,
                                                  char* __restrict__ h3p) {
  const int D3 = 262144, PD = 66, PD3 = PD * PD * PD;
  const int N3 = 34 * 34 * 34, N4 = 18 * 18 * 18;
  int idx = blockIdx.x * 256 + threadIdx.x;
  int b = blockIdx.y;
  if (idx < PD3) {
    int pv = idx;
    int pw = pv % PD; int t = pv / PD; int ph = t % PD; int pd = t / PD;
    half4 o = {};
    if (pw > 0 && pw < 65 && ph > 0 && ph < 65 && pd > 0 && pd < 65) {
      int v = (((pd - 1) * 64) + (ph - 1)) * 64 + (pw - 1);
      if (mask[(size_t)b * D3 + v] < 1) {
        const float* xb = x + (size_t)b * 3 * D3 + v;
        o[0] = (f16)xb[0];
        o[1] = (f16)xb[D3];
        o[2] = (f16)xb[2 * D3];
      }
    }
    *reinterpret_cast<half4*>(xcp + ((size_t)b * PD3 + pv) * 4) = o;
    return;
  }
  idx -= PD3;
  if (idx < PD3) { zb_one<66, 128>(h1p, idx, b); return; }
  idx -= PD3;
  if (idx < N3) { zb_one<34, 256>(h2p, idx, b); return; }
  idx -= N3;
  if (idx < N4) zb_one<18, 512>(h3p, idx, b);
}

// ===================== mask pyramid =====================
__global__ __launch_bounds__(256) void dil_w_k(const int* __restrict__ mask,
                                               unsigned char* __restrict__ aw) {
  const int D3 = 262144;
  int t = blockIdx.x * 256 + threadIdx.x;
  int b = t >> 16;
  int v = (t & 65535) * 4;
  int w0 = v & 63;
  const int* mb = mask + (size_t)b * D3;
  int a[6];
  a[0] = (w0 > 0) ? (mb[v - 1] < 1) : 0;
  #pragma unroll
  for (int i = 0; i < 4; i++) a[i + 1] = mb[v + i] < 1;
  a[5] = (w0 < 60) ? (mb[v + 4] < 1) : 0;
  unsigned int o = 0;
  #pragma unroll
  for (int i = 0; i < 4; i++)
    o |= ((unsigned)(a[i] | a[i + 1] | a[i + 2])) << (8 * i);
  *reinterpret_cast<unsigned int*>(aw + (size_t)b * D3 + v) = o;
}

// merged h+d dilation: m1 = OR over 3x3 (h,d) window of aw
__global__ __launch_bounds__(256) void dil_hd2_k(const unsigned char* __restrict__ aw,
                                                 unsigned char* __restrict__ m1) {
  const int D3 = 262144;
  int t = blockIdx.x * 256 + threadIdx.x;
  int b = t >> 16;
  int v = (t & 65535) * 4;
  int h = (v >> 6) & 63;
  int d = v >> 12;
  const unsigned char* ib = aw + (size_t)b * D3;
  unsigned int m = 0;
  #pragma unroll
  for (int dd = -1; dd <= 1; dd++) {
    int id = d + dd; if ((unsigned)id >= 64u) continue;
    #pragma unroll
    for (int hh = -1; hh <= 1; hh++) {
      int ih = h + hh; if ((unsigned)ih >= 64u) continue;
      m |= *reinterpret_cast<const unsigned int*>(ib + ((id << 12) | (ih << 6) | (v & 63)));
    }
  }
  *reinterpret_cast<unsigned int*>(m1 + (size_t)b * D3 + v) = m;
}

// m2/m3/m4 direct from m1 (windows 3/7/15 at strides 2/4/8) + zero d_out, one launch.
__global__ __launch_bounds__(256) void dil_rest_k(const unsigned char* __restrict__ m1,
                                                  unsigned char* __restrict__ m2,
                                                  unsigned char* __restrict__ m3,
                                                  unsigned char* __restrict__ m4,
                                                  float* __restrict__ outp) {
  const int D = 64, D3 = 262144;
  const int S2 = BATCH * 32768, S3 = BATCH * 4096, S4 = BATCH * 512;
  int idx = blockIdx.x * 256 + threadIdx.x;
  int b, v, LOGD, H, ST;
  unsigned char* mo;
  if (idx < S2)                 { b = idx >> 15; v = idx & 32767; LOGD = 5; H = 1; ST = 2; mo = m2 + (size_t)b * 32768; }
  else if ((idx -= S2) < S3)    { b = idx >> 12; v = idx & 4095;  LOGD = 4; H = 3; ST = 4; mo = m3 + (size_t)b * 4096; }
  else if ((idx -= S3) < S4)    { b = idx >> 9;  v = idx & 511;   LOGD = 3; H = 7; ST = 8; mo = m4 + (size_t)b * 512; }
  else if ((idx -= S4) < 2048)  { outp[idx] = 0.f; return; }
  else return;
  int DM = (1 << LOGD) - 1;
  int ow = v & DM, oh = (v >> LOGD) & DM, od = v >> (2 * LOGD);
  const unsigned char* mb = m1 + (size_t)b * D3;
  int act = 0;
  for (int dd = -H; dd <= H && !act; dd++) {
    int id = od * ST + dd; if ((unsigned)id >= (unsigned)D) continue;
    for (int hh = -H; hh <= H && !act; hh++) {
      int ih = oh * ST + hh; if ((unsigned)ih >= (unsigned)D) continue;
      for (int ww = -H; ww <= H; ww++) {
        int iw = ow * ST + ww; if ((unsigned)iw >= (unsigned)D) continue;
        if (mb[((size_t)id * D + ih) * D + iw]) { act = 1; break; }
      }
    }
  }
  mo[v] = (unsigned char)act;
}

// ===================== conv1 via MFMA — halo-tile staging (R16-proven) =====================
template<int BM>
__global__ __launch_bounds__(256) void conv1_mfma_k(const f16* __restrict__ xcp,
                                                    const f16* __restrict__ w1f,
                                                    const float* __restrict__ bias,
                                                    const unsigned char* __restrict__ mo,
                                                    f16* __restrict__ out /* h1p padded */) {
  const int D3 = 262144, COUT = 64, PD = 66, PD3 = PD * PD * PD;
  constexpr int K = 128, LDB = K + 8;
  constexpr int WM = 2, WN = 2;
  constexpr int MF = BM / (16 * WM), NF = 64 / (16 * WN);
  __shared__ __align__(16) f16 halo[1056 * 4];
  __shared__ __align__(16) f16 Bs[64][LDB];

  const int tid = threadIdx.x, lane = tid & 63, wave = tid >> 6;
  const int wm = wave >> 1, wn = wave & 1;
  const int v0 = blockIdx.x * BM;
  const int b = blockIdx.y;
  const int oh0 = (v0 >> 6) & 63, od = v0 >> 12;
  const f16* xb = xcp + (size_t)b * PD3 * 4;

  for (int c = tid; c < 64 * (K / 8); c += 256) {
    int row = c >> 4, cc = c & 15;
    *reinterpret_cast<half8*>(&Bs[row][cc * 8]) =
        *reinterpret_cast<const half8*>(w1f + row * K + cc * 8);
  }
  for (int e = tid; e < 1056; e += 256) {
    half4 val = {};
    if (e < 792) {
      int d = e / 264, r = e - d * 264, h = r / 66, w = r - h * 66;
      val = *reinterpret_cast<const half4*>(
          xb + (((size_t)(od + d) * PD + (oh0 + h)) * PD + w) * 4);
    }
    *reinterpret_cast<half4*>(&halo[(size_t)e * 4]) = val;
  }
  __syncthreads();

  const int ll = lane & 15, lh = lane >> 4;
  int koff[8];
  #pragma unroll
  for (int i = 0; i < 8; i++) {
    int ks = (i >> 1) * 8 + 2 * lh + (i & 1);
    int kd = ks / 9, rr = ks - kd * 9, kh = rr / 3, kw = rr - kh * 3;
    koff[i] = ((kd * 4 + kh) * 66 + kw) * 4;
  }
  const int lbase = (wm * 66 + ll) * 4;

  f32x4 acc[MF][NF] = {};
  #pragma unroll
  for (int q = 0; q < 4; q++) {
    half8 a[MF], bb[NF];
    #pragma unroll
    for (int mf = 0; mf < MF; mf++) {
      half4 lo = *reinterpret_cast<const half4*>(&halo[lbase + mf * 64 + koff[q * 2]]);
      half4 hi = *reinterpret_cast<const half4*>(&halo[lbase + mf * 64 + koff[q * 2 + 1]]);
      a[mf] = half8{lo[0], lo[1], lo[2], lo[3], hi[0], hi[1], hi[2], hi[3]};
    }
    #pragma unroll
    for (int nf = 0; nf < NF; nf++)
      bb[nf] = *reinterpret_cast<const half8*>(&Bs[wn * NF * 16 + nf * 16 + ll][q * 32 + lh * 8]);
    #pragma unroll
    for (int mf = 0; mf < MF; mf++)
      #pragma unroll
      for (int nf = 0; nf < NF; nf++)
        acc[mf][nf] = __builtin_amdgcn_mfma_f32_16x16x32_f16(a[mf], bb[nf], acc[mf][nf], 0, 0, 0);
  }

  const unsigned char* mb = mo + (size_t)b * D3;
  f16* ob = out + (size_t)b * PD3 * COUT;
  float bv[NF];
  #pragma unroll
  for (int nf = 0; nf < NF; nf++) bv[nf] = bias[wn * NF * 16 + nf * 16 + ll];
  #pragma unroll
  for (int mf = 0; mf < MF; mf++) {
    #pragma unroll
    for (int r = 0; r < 4; r++) {
      int v = v0 + wm * MF * 16 + mf * 16 + (lh << 2) + r;
      bool act = mb[v] != 0;
      int ow = v & 63, oh = (v >> 6) & 63, odv = v >> 12;
      size_t pv = ((size_t)(odv + 1) * PD + oh + 1) * PD + ow + 1;
      #pragma unroll
      for (int nf = 0; nf < NF; nf++) {
        int co = wn * NF * 16 + nf * 16 + ll;
        float val = acc[mf][nf][r] + bv[nf];
        val = act ? (val > 0.f ? val : 0.f) : 0.f;
        ob[pv * COUT + co] = (f16)val;
      }
    }
  }
}

// ===================== stride-2 conv, 2-phase dbuf MFMA (R8/R11-proven structure) =====================
template<int CINS, int CINF, int COUT, int DIN, int DOUT, int BM, int BN,
         int WM, int WN, int SWZ, int OP, int BMERGE, int POOL>
__global__ __launch_bounds__(WM * WN * 64) void conv_mfma2_k(const f16* __restrict__ in,
                                                             const f16* __restrict__ w27,
                                                             const float* __restrict__ bias,
                                                             const unsigned char* __restrict__ mo,
                                                             f16* __restrict__ out,
                                                             float* __restrict__ poolp) {
  constexpr int PD = DIN + 2, PDo = DOUT + 2;
  constexpr int NW = WM * WN;
  constexpr int MF = BM / (16 * WM), NF = BN / (16 * WN);
  constexpr int ROWB = CINS * 2;
  constexpr int ROWBF = CINF * 2;
  constexpr int CHUNKS = ROWB / 16;
  constexpr int RPI = 64 / CHUNKS;
  constexpr int A_IW = BM / RPI / NW;
  constexpr int B_IW = BN / RPI / NW;
  constexpr int CIH = CINF / CINS;
  constexpr int NSTEP = 27 * CIH;
  constexpr int CI0S = CINS / 32;
  constexpr int D3o = DOUT * DOUT * DOUT;
  constexpr int LOGD = (DOUT == 32) ? 5 : ((DOUT == 16) ? 4 : 3);

  __shared__ __align__(16) char As[2][BM * ROWB];
  __shared__ __align__(16) char Bs[2][BN * ROWB];

  const int tid = threadIdx.x, lane = tid & 63, wave = tid >> 6;
  const int wm = wave / WN, wn = wave % WN;
  int bx = blockIdx.x;
  if (SWZ) {
    int cpx = gridDim.x >> 3;
    bx = (bx & 7) * cpx + (bx >> 3);
  }
  const int v0 = bx * BM, co0 = blockIdx.y * BN;
  const int bz = BMERGE ? 0 : blockIdx.z;

  auto key = [](int r) -> int { return (CHUNKS >= 8) ? (r & 7) : ((r >> 1) & 3); };

  const int lrow = lane / CHUNKS;
  const int lchunk = lane % CHUNKS;
  const char* a_src[A_IW];
  #pragma unroll
  for (int i = 0; i < A_IW; i++) {
    int r = (wave * A_IW + i) * RPI + lrow;
    int v = v0 + r;
    int vb = BMERGE ? (v >> (3 * LOGD)) : bz;
    int vv = BMERGE ? (v & (D3o - 1)) : v;
    int ow = vv & (DOUT - 1), oh = (vv >> LOGD) & (DOUT - 1), od = vv >> (2 * LOGD);
    size_t flat = (size_t)vb * PD * PD * PD + ((size_t)(2 * od) * PD + 2 * oh) * PD + 2 * ow;
    a_src[i] = (const char*)in + flat * ROWBF + (lchunk ^ key(r)) * 16;
  }
  const char* b_src[B_IW];
  #pragma unroll
  for (int i = 0; i < B_IW; i++) {
    int r = (wave * B_IW + i) * RPI + lrow;
    b_src[i] = (const char*)w27 + (size_t)(co0 + r) * ROWBF + (lchunk ^ key(r)) * 16;
  }

  auto stage = [&](int buf, int s) {
    int k = s / CIH;
    int h = s - k * CIH;
    int kd = k / 9, r2 = k - kd * 9, kh = r2 / 3, kw = r2 - kh * 3;
    int koff = ((kd * PD + kh) * PD + kw) * ROWBF + h * ROWB;
    #pragma unroll
    for (int i = 0; i < A_IW; i++)
      gload16(a_src[i] + koff, &As[buf][(wave * A_IW + i) * 1024]);
    size_t wko = (size_t)k * COUT * ROWBF + h * ROWB;
    #pragma unroll
    for (int i = 0; i < B_IW; i++)
      gload16(b_src[i] + wko, &Bs[buf][(wave * B_IW + i) * 1024]);
  };

  f32x4 acc[MF][NF] = {};
  const int ll = lane & 15, lh = lane >> 4;
  const int ra0 = wm * MF * 16 + ll;
  const int rb0 = wn * NF * 16 + ll;
  const int rswa = key(ra0);
  const int rswb = key(rb0);

  stage(0, 0);
  __syncthreads();
  int cur = 0;
  for (int s = 0; s < NSTEP; s++) {
    if (s < NSTEP - 1) stage(cur ^ 1, s + 1);
    #pragma unroll
    for (int c = 0; c < CI0S; c++) {
      const int q = c * 4 + lh;
      half8 a[MF], bb[NF];
      #pragma unroll
      for (int mf = 0; mf < MF; mf++)
        a[mf] = *reinterpret_cast<const half8*>(
            &As[cur][(ra0 + mf * 16) * ROWB + ((q ^ rswa) * 16)]);
      #pragma unroll
      for (int nf = 0; nf < NF; nf++)
        bb[nf] = *reinterpret_cast<const half8*>(
            &Bs[cur][(rb0 + nf * 16) * ROWB + ((q ^ rswb) * 16)]);
      #pragma unroll
      for (int mf = 0; mf < MF; mf++)
        #pragma unroll
        for (int nf = 0; nf < NF; nf++)
          acc[mf][nf] = __builtin_amdgcn_mfma_f32_16x16x32_f16(a[mf], bb[nf], acc[mf][nf], 0, 0, 0);
    }
    __syncthreads();
    cur ^= 1;
  }

  f16* ob = out;
  float bv[NF];
  #pragma unroll
  for (int nf = 0; nf < NF; nf++) bv[nf] = bias[co0 + wn * NF * 16 + nf * 16 + ll];
  float pmax[NF];
  #pragma unroll
  for (int nf = 0; nf < NF; nf++) pmax[nf] = 0.f;
  #pragma unroll
  for (int mf = 0; mf < MF; mf++) {
    #pragma unroll
    for (int r = 0; r < 4; r++) {
      int v = v0 + wm * MF * 16 + mf * 16 + (lh << 2) + r;
      int vb = BMERGE ? (v >> (3 * LOGD)) : bz;
      int vv = BMERGE ? (v & (D3o - 1)) : v;
      bool act = mo[(size_t)vb * D3o + vv] != 0;
      int ow = vv & (DOUT - 1), oh = (vv >> LOGD) & (DOUT - 1), od = vv >> (2 * LOGD);
      size_t pv = OP ? (((size_t)(od + 1) * PDo + oh + 1) * PDo + ow + 1) : (size_t)vv;
      size_t obase = ((size_t)vb * (OP ? PDo * PDo * PDo : D3o) + pv) * COUT;
      #pragma unroll
      for (int nf = 0; nf < NF; nf++) {
        int co = co0 + wn * NF * 16 + nf * 16 + ll;
        float val = acc[mf][nf][r] + bv[nf];
        val = act ? (val > 0.f ? val : 0.f) : 0.f;
        if constexpr (POOL) {
          pmax[nf] = fmaxf(pmax[nf], val);
        } else {
          ob[obase + co] = (f16)val;
        }
      }
    }
  }
  if constexpr (POOL) {
    #pragma unroll
    for (int nf = 0; nf < NF; nf++) {
      int co = co0 + wn * NF * 16 + nf * 16 + ll;
      atomicMax((int*)poolp + bz * 512 + co, __float_as_int(pmax[nf]));
    }
  }
}

extern "C" void kernel_launch(void* const* d_in, const int* in_sizes, int n_in,
                              void* d_out, int out_size, void* d_ws, size_t ws_size,
                              hipStream_t stream) {
  const float* x    = (const float*)d_in[0];
  const int*   mask = (const int*)d_in[1];
  const float* w1 = (const float*)d_in[2];
  const float* b1 = (const float*)d_in[3];
  const float* w2 = (const float*)d_in[4];
  const float* b2 = (const float*)d_in[5];
  const float* w3 = (const float*)d_in[6];
  const float* b3 = (const float*)d_in[7];
  const float* w4 = (const float*)d_in[8];
  const float* b4 = (const float*)d_in[9];
  float* outp = (float*)d_out;

  const size_t PD1 = 66 * 66 * 66;   // 287496
  const size_t PD2 = 34 * 34 * 34;   // 39304
  const size_t PD3s = 18 * 18 * 18;  // 5832

  char* ws = (char*)d_ws;
  size_t off = 0;
  auto alloc = [&](size_t bytes) -> char* {
    char* p = ws + off;
    off = (off + bytes + 255) & ~(size_t)255;
    return p;
  };
  f16* wf1 = (f16*)alloc((size_t)64 * 128 * 2);
  f16* wf2 = (f16*)alloc((size_t)27 * 128 * 64 * 2);
  f16* wf3 = (f16*)alloc((size_t)27 * 256 * 128 * 2);
  f16* wf4 = (f16*)alloc((size_t)27 * 512 * 256 * 2);
  unsigned char* aw = (unsigned char*)alloc((size_t)BATCH * 262144);
  unsigned char* m1 = (unsigned char*)alloc((size_t)BATCH * 262144);
  unsigned char* m2 = (unsigned char*)alloc((size_t)BATCH * 32768);
  unsigned char* m3 = (unsigned char*)alloc((size_t)BATCH * 4096);
  unsigned char* m4 = (unsigned char*)alloc((size_t)BATCH * 512);
  f16* h1p = (f16*)alloc((size_t)BATCH * PD1 * 64 * 2);    // 147 MB
  f16* h2p = (f16*)alloc((size_t)BATCH * PD2 * 128 * 2);   // 40 MB
  f16* h3p = (f16*)alloc((size_t)BATCH * PD3s * 256 * 2);  // 12 MB
  f16* xcp = (f16*)alloc((size_t)BATCH * PD1 * 4 * 2);     // 9.2 MB
  if (off > ws_size) return;

  // merged weight prep (1 launch)
  {
    const int TOT = 64 * 128 + 27 * 128 * 64 + 27 * 256 * 128 + 27 * 512 * 256;
    wprep_all_k<<<dim3((TOT + 255) / 256), 256, 0, stream>>>(w1, w2, w3, w4, wf1, wf2, wf3, wf4);
  }

  // mask pyramid
  dil_w_k<<<dim3(BATCH * 65536 / 256), 256, 0, stream>>>(mask, aw);
  dil_hd2_k<<<dim3(BATCH * 65536 / 256), 256, 0, stream>>>(aw, m1);
  {
    const int TOT = BATCH * 32768 + BATCH * 4096 + BATCH * 512 + 2048;
    dil_rest_k<<<dim3((TOT + 255) / 256), 256, 0, stream>>>(m1, m2, m3, m4, outp);
  }

  // merged prep: xcp fill + h1p/h2p/h3p border zero (1 launch)
  {
    const int TOT = 287496 * 2 + 39304 + 5832;
    prep_all_k<<<dim3((TOT + 255) / 256, BATCH), 256, 0, stream>>>(
        x, mask, xcp, (char*)h1p, (char*)h2p, (char*)h3p);
  }

  // conv1 (halo-tile staging)
  conv1_mfma_k<128><<<dim3(262144 / 128, BATCH), 256, 0, stream>>>(xcp, wf1, b1, m1, h1p);

  // conv2: CINS64, BM64 BN128 MF2xNF4, 48KB LDS -> 3 blocks/CU, grid 512x1x4, SWZ
  conv_mfma2_k<64, 64, 128, 64, 32, 64, 128, 2, 2, 1, 1, 0, 0>
      <<<dim3(512, 1, BATCH), 256, 0, stream>>>(h1p, wf2, b2, m2, h2p, nullptr);
  // conv3: batch-merged M=16384, CINS64 ci-split2, BM64 BN128, 48KB, grid 256x2, SWZ
  conv_mfma2_k<64, 128, 256, 32, 16, 64, 128, 2, 2, 1, 1, 1, 0>
      <<<dim3(256, 2, 1), 256, 0, stream>>>(h2p, wf3, b3, m3, h3p, nullptr);
  // conv4: CINS128 ci-split2, BM32 BN64, 2 waves, 48KB, grid 16x8x4 — POOL fused (atomicMax)
  conv_mfma2_k<128, 256, 512, 16, 8, 32, 64, 1, 2, 0, 0, 0, 1>
      <<<dim3(16, 8, BATCH), 128, 0, stream>>>(h3p, wf4, b4, m4, nullptr, outp);
}

// Round 19
// 284.206 us; speedup vs baseline: 1.0700x; 1.0042x over previous
//
#include <hip/hip_runtime.h>

typedef _Float16 f16;
typedef _Float16 half4 __attribute__((ext_vector_type(4)));
typedef _Float16 half8 __attribute__((ext_vector_type(8)));
typedef float f32x4 __attribute__((ext_vector_type(4)));

#define BATCH 4

// async global -> LDS, 16B per lane; dest = wave-uniform base + lane*16
__device__ __forceinline__ void gload16(const void* g, void* l) {
  __builtin_amdgcn_global_load_lds((const __attribute__((address_space(1))) unsigned int*)g,
                                   (__attribute__((address_space(3))) unsigned int*)l, 16, 0, 0);
}

// ===================== border-zero helper =====================
template<int DP, int ROWB>
__device__ __forceinline__ void zb_one(char* __restrict__ buf, int v, int b) {
  int w = v % DP; int t = v / DP; int h = t % DP; int d = t / DP;
  bool border = (w == 0) | (w == DP - 1) | (h == 0) | (h == DP - 1) | (d == 0) | (d == DP - 1);
  if (!border) return;
  char* p = buf + ((size_t)b * DP * DP * DP + v) * ROWB;
  #pragma unroll
  for (int i = 0; i < ROWB; i += 8)
    *reinterpret_cast<unsigned long long*>(p + i) = 0ull;
}

// ===================== merged weight prep (1 launch) =====================
__global__ __launch_bounds__(256) void wprep_all_k(const float* __restrict__ w1,
                                                   const float* __restrict__ w2,
                                                   const float* __restrict__ w3,
                                                   const float* __restrict__ w4,
                                                   f16* __restrict__ wf1,
                                                   f16* __restrict__ wf2,
                                                   f16* __restrict__ wf3,
                                                   f16* __restrict__ wf4) {
  const int T1 = 64 * 128;
  const int T2 = 27 * 128 * 64;
  const int T3 = 27 * 256 * 128;
  const int T4 = 27 * 512 * 256;
  int idx = blockIdx.x * 256 + threadIdx.x;
  if (idx < T1) {
    int q = idx & 127, co = idx >> 7;
    int k = q >> 2, ci = q & 3;
    float v = (ci < 3 && k < 27) ? w1[(co * 3 + ci) * 27 + k] : 0.f;
    wf1[idx] = (f16)v;
    return;
  }
  idx -= T1;
  const float* w; f16* wo; int COUT, CIN;
  if (idx < T2)       { w = w2; wo = wf2; COUT = 128; CIN = 64; }
  else if ((idx -= T2) < T3) { w = w3; wo = wf3; COUT = 256; CIN = 128; }
  else if ((idx -= T3) < T4) { w = w4; wo = wf4; COUT = 512; CIN = 256; }
  else return;
  int k = idx % 27;
  int t = idx / 27;
  int ci = t % CIN;
  int co = t / CIN;
  wo[((size_t)k * COUT + co) * CIN + ci] = (f16)w[idx];
}

// ===================== merged pre-conv1 prep: xcp fill + h1p/h2p/h3p border zero =====================
__global__ __launch_bounds__(256) void prep_all_k(const float* __restrict__ x,
                                                  const int* __restrict__ mask,
                                                  f16* __restrict__ xcp,
                                                  char* __restrict__ h1p,
                                                  char* __restrict__ h2p,
                                                  char* __restrict__ h3p) {
  const int D3 = 262144, PD = 66, PD3 = PD * PD * PD;
  const int N3 = 34 * 34 * 34, N4 = 18 * 18 * 18;
  int idx = blockIdx.x * 256 + threadIdx.x;
  int b = blockIdx.y;
  if (idx < PD3) {
    int pv = idx;
    int pw = pv % PD; int t = pv / PD; int ph = t % PD; int pd = t / PD;
    half4 o = {};
    if (pw > 0 && pw < 65 && ph > 0 && ph < 65 && pd > 0 && pd < 65) {
      int v = (((pd - 1) * 64) + (ph - 1)) * 64 + (pw - 1);
      if (mask[(size_t)b * D3 + v] < 1) {
        const float* xb = x + (size_t)b * 3 * D3 + v;
        o[0] = (f16)xb[0];
        o[1] = (f16)xb[D3];
        o[2] = (f16)xb[2 * D3];
      }
    }
    *reinterpret_cast<half4*>(xcp + ((size_t)b * PD3 + pv) * 4) = o;
    return;
  }
  idx -= PD3;
  if (idx < PD3) { zb_one<66, 128>(h1p, idx, b); return; }
  idx -= PD3;
  if (idx < N3) { zb_one<34, 256>(h2p, idx, b); return; }
  idx -= N3;
  if (idx < N4) zb_one<18, 512>(h3p, idx, b);
}

// ===================== mask pyramid =====================
__global__ __launch_bounds__(256) void dil_w_k(const int* __restrict__ mask,
                                               unsigned char* __restrict__ aw) {
  const int D3 = 262144;
  int t = blockIdx.x * 256 + threadIdx.x;
  int b = t >> 16;
  int v = (t & 65535) * 4;
  int w0 = v & 63;
  const int* mb = mask + (size_t)b * D3;
  int a[6];
  a[0] = (w0 > 0) ? (mb[v - 1] < 1) : 0;
  #pragma unroll
  for (int i = 0; i < 4; i++) a[i + 1] = mb[v + i] < 1;
  a[5] = (w0 < 60) ? (mb[v + 4] < 1) : 0;
  unsigned int o = 0;
  #pragma unroll
  for (int i = 0; i < 4; i++)
    o |= ((unsigned)(a[i] | a[i + 1] | a[i + 2])) << (8 * i);
  *reinterpret_cast<unsigned int*>(aw + (size_t)b * D3 + v) = o;
}

// merged h+d dilation: m1 = OR over 3x3 (h,d) window of aw
__global__ __launch_bounds__(256) void dil_hd2_k(const unsigned char* __restrict__ aw,
                                                 unsigned char* __restrict__ m1) {
  const int D3 = 262144;
  int t = blockIdx.x * 256 + threadIdx.x;
  int b = t >> 16;
  int v = (t & 65535) * 4;
  int h = (v >> 6) & 63;
  int d = v >> 12;
  const unsigned char* ib = aw + (size_t)b * D3;
  unsigned int m = 0;
  #pragma unroll
  for (int dd = -1; dd <= 1; dd++) {
    int id = d + dd; if ((unsigned)id >= 64u) continue;
    #pragma unroll
    for (int hh = -1; hh <= 1; hh++) {
      int ih = h + hh; if ((unsigned)ih >= 64u) continue;
      m |= *reinterpret_cast<const unsigned int*>(ib + ((id << 12) | (ih << 6) | (v & 63)));
    }
  }
  *reinterpret_cast<unsigned int*>(m1 + (size_t)b * D3 + v) = m;
}

// m2/m3/m4 direct from m1 (windows 3/7/15 at strides 2/4/8) + zero d_out, one launch.
__global__ __launch_bounds__(256) void dil_rest_k(const unsigned char* __restrict__ m1,
                                                  unsigned char* __restrict__ m2,
                                                  unsigned char* __restrict__ m3,
                                                  unsigned char* __restrict__ m4,
                                                  float* __restrict__ outp) {
  const int D = 64, D3 = 262144;
  const int S2 = BATCH * 32768, S3 = BATCH * 4096, S4 = BATCH * 512;
  int idx = blockIdx.x * 256 + threadIdx.x;
  int b, v, LOGD, H, ST;
  unsigned char* mo;
  if (idx < S2)                 { b = idx >> 15; v = idx & 32767; LOGD = 5; H = 1; ST = 2; mo = m2 + (size_t)b * 32768; }
  else if ((idx -= S2) < S3)    { b = idx >> 12; v = idx & 4095;  LOGD = 4; H = 3; ST = 4; mo = m3 + (size_t)b * 4096; }
  else if ((idx -= S3) < S4)    { b = idx >> 9;  v = idx & 511;   LOGD = 3; H = 7; ST = 8; mo = m4 + (size_t)b * 512; }
  else if ((idx -= S4) < 2048)  { outp[idx] = 0.f; return; }
  else return;
  int DM = (1 << LOGD) - 1;
  int ow = v & DM, oh = (v >> LOGD) & DM, od = v >> (2 * LOGD);
  const unsigned char* mb = m1 + (size_t)b * D3;
  int act = 0;
  for (int dd = -H; dd <= H && !act; dd++) {
    int id = od * ST + dd; if ((unsigned)id >= (unsigned)D) continue;
    for (int hh = -H; hh <= H && !act; hh++) {
      int ih = oh * ST + hh; if ((unsigned)ih >= (unsigned)D) continue;
      for (int ww = -H; ww <= H; ww++) {
        int iw = ow * ST + ww; if ((unsigned)iw >= (unsigned)D) continue;
        if (mb[((size_t)id * D + ih) * D + iw]) { act = 1; break; }
      }
    }
  }
  mo[v] = (unsigned char)act;
}

// ===================== conv1 via MFMA — halo-tile staging (R16-proven) =====================
template<int BM>
__global__ __launch_bounds__(256) void conv1_mfma_k(const f16* __restrict__ xcp,
                                                    const f16* __restrict__ w1f,
                                                    const float* __restrict__ bias,
                                                    const unsigned char* __restrict__ mo,
                                                    f16* __restrict__ out /* h1p padded */) {
  const int D3 = 262144, COUT = 64, PD = 66, PD3 = PD * PD * PD;
  constexpr int K = 128, LDB = K + 8;
  constexpr int WM = 2, WN = 2;
  constexpr int MF = BM / (16 * WM), NF = 64 / (16 * WN);
  __shared__ __align__(16) f16 halo[1056 * 4];
  __shared__ __align__(16) f16 Bs[64][LDB];

  const int tid = threadIdx.x, lane = tid & 63, wave = tid >> 6;
  const int wm = wave >> 1, wn = wave & 1;
  const int v0 = blockIdx.x * BM;
  const int b = blockIdx.y;
  const int oh0 = (v0 >> 6) & 63, od = v0 >> 12;
  const f16* xb = xcp + (size_t)b * PD3 * 4;

  for (int c = tid; c < 64 * (K / 8); c += 256) {
    int row = c >> 4, cc = c & 15;
    *reinterpret_cast<half8*>(&Bs[row][cc * 8]) =
        *reinterpret_cast<const half8*>(w1f + row * K + cc * 8);
  }
  for (int e = tid; e < 1056; e += 256) {
    half4 val = {};
    if (e < 792) {
      int d = e / 264, r = e - d * 264, h = r / 66, w = r - h * 66;
      val = *reinterpret_cast<const half4*>(
          xb + (((size_t)(od + d) * PD + (oh0 + h)) * PD + w) * 4);
    }
    *reinterpret_cast<half4*>(&halo[(size_t)e * 4]) = val;
  }
  __syncthreads();

  const int ll = lane & 15, lh = lane >> 4;
  int koff[8];
  #pragma unroll
  for (int i = 0; i < 8; i++) {
    int ks = (i >> 1) * 8 + 2 * lh + (i & 1);
    int kd = ks / 9, rr = ks - kd * 9, kh = rr / 3, kw = rr - kh * 3;
    koff[i] = ((kd * 4 + kh) * 66 + kw) * 4;
  }
  const int lbase = (wm * 66 + ll) * 4;

  f32x4 acc[MF][NF] = {};
  #pragma unroll
  for (int q = 0; q < 4; q++) {
    half8 a[MF], bb[NF];
    #pragma unroll
    for (int mf = 0; mf < MF; mf++) {
      half4 lo = *reinterpret_cast<const half4*>(&halo[lbase + mf * 64 + koff[q * 2]]);
      half4 hi = *reinterpret_cast<const half4*>(&halo[lbase + mf * 64 + koff[q * 2 + 1]]);
      a[mf] = half8{lo[0], lo[1], lo[2], lo[3], hi[0], hi[1], hi[2], hi[3]};
    }
    #pragma unroll
    for (int nf = 0; nf < NF; nf++)
      bb[nf] = *reinterpret_cast<const half8*>(&Bs[wn * NF * 16 + nf * 16 + ll][q * 32 + lh * 8]);
    #pragma unroll
    for (int mf = 0; mf < MF; mf++)
      #pragma unroll
      for (int nf = 0; nf < NF; nf++)
        acc[mf][nf] = __builtin_amdgcn_mfma_f32_16x16x32_f16(a[mf], bb[nf], acc[mf][nf], 0, 0, 0);
  }

  const unsigned char* mb = mo + (size_t)b * D3;
  f16* ob = out + (size_t)b * PD3 * COUT;
  float bv[NF];
  #pragma unroll
  for (int nf = 0; nf < NF; nf++) bv[nf] = bias[wn * NF * 16 + nf * 16 + ll];
  #pragma unroll
  for (int mf = 0; mf < MF; mf++) {
    #pragma unroll
    for (int r = 0; r < 4; r++) {
      int v = v0 + wm * MF * 16 + mf * 16 + (lh << 2) + r;
      bool act = mb[v] != 0;
      int ow = v & 63, oh = (v >> 6) & 63, odv = v >> 12;
      size_t pv = ((size_t)(odv + 1) * PD + oh + 1) * PD + ow + 1;
      #pragma unroll
      for (int nf = 0; nf < NF; nf++) {
        int co = wn * NF * 16 + nf * 16 + ll;
        float val = acc[mf][nf][r] + bv[nf];
        val = act ? (val > 0.f ? val : 0.f) : 0.f;
        ob[pv * COUT + co] = (f16)val;
      }
    }
  }
}

// ===================== stride-2 conv, 2-phase dbuf MFMA (R18 structure; saddr-form staging) =====================
// Staging addresses: uniform per-step base pointer (SALU) + per-lane 32-bit offset (VGPR)
// -> clang can emit global_load_lds saddr form; removes 64-bit per-lane pointer adds
// from the per-step critical path and frees ~6 VGPR. All per-lane offsets < 2^31.
template<int CINS, int CINF, int COUT, int DIN, int DOUT, int BM, int BN,
         int WM, int WN, int SWZ, int OP, int BMERGE, int POOL>
__global__ __launch_bounds__(WM * WN * 64) void conv_mfma2_k(const f16* __restrict__ in,
                                                             const f16* __restrict__ w27,
                                                             const float* __restrict__ bias,
                                                             const unsigned char* __restrict__ mo,
                                                             f16* __restrict__ out,
                                                             float* __restrict__ poolp) {
  constexpr int PD = DIN + 2, PDo = DOUT + 2;
  constexpr int NW = WM * WN;
  constexpr int MF = BM / (16 * WM), NF = BN / (16 * WN);
  constexpr int ROWB = CINS * 2;
  constexpr int ROWBF = CINF * 2;
  constexpr int CHUNKS = ROWB / 16;
  constexpr int RPI = 64 / CHUNKS;
  constexpr int A_IW = BM / RPI / NW;
  constexpr int B_IW = BN / RPI / NW;
  constexpr int CIH = CINF / CINS;
  constexpr int NSTEP = 27 * CIH;
  constexpr int CI0S = CINS / 32;
  constexpr int D3o = DOUT * DOUT * DOUT;
  constexpr int LOGD = (DOUT == 32) ? 5 : ((DOUT == 16) ? 4 : 3);

  __shared__ __align__(16) char As[2][BM * ROWB];
  __shared__ __align__(16) char Bs[2][BN * ROWB];

  const int tid = threadIdx.x, lane = tid & 63, wave = tid >> 6;
  const int wm = wave / WN, wn = wave % WN;
  int bx = blockIdx.x;
  if (SWZ) {
    int cpx = gridDim.x >> 3;
    bx = (bx & 7) * cpx + (bx >> 3);
  }
  const int v0 = bx * BM, co0 = blockIdx.y * BN;
  const int bz = BMERGE ? 0 : blockIdx.z;

  auto key = [](int r) -> int { return (CHUNKS >= 8) ? (r & 7) : ((r >> 1) & 3); };

  // uniform base (SGPR): batch slice for non-BMERGE; 'in' itself for BMERGE (vb in offset)
  const char* ibz = (const char*)in + (size_t)bz * PD * PD * PD * ROWBF;
  const char* wb = (const char*)w27;

  // ---- per-lane 32-bit offsets (computed once) ----
  const int lrow = lane / CHUNKS;
  const int lchunk = lane % CHUNKS;
  int a_off[A_IW];
  #pragma unroll
  for (int i = 0; i < A_IW; i++) {
    int r = (wave * A_IW + i) * RPI + lrow;
    int v = v0 + r;
    int vb = BMERGE ? (v >> (3 * LOGD)) : 0;
    int vv = BMERGE ? (v & (D3o - 1)) : v;
    int ow = vv & (DOUT - 1), oh = (vv >> LOGD) & (DOUT - 1), od = vv >> (2 * LOGD);
    int flat = vb * (PD * PD * PD) + ((2 * od) * PD + 2 * oh) * PD + 2 * ow;
    a_off[i] = flat * ROWBF + (lchunk ^ key(r)) * 16;
  }
  int b_off[B_IW];
  #pragma unroll
  for (int i = 0; i < B_IW; i++) {
    int r = (wave * B_IW + i) * RPI + lrow;
    b_off[i] = (co0 + r) * ROWBF + (lchunk ^ key(r)) * 16;
  }

  auto stage = [&](int buf, int s) {
    int k = s / CIH;
    int h = s - k * CIH;
    int kd = k / 9, r2 = k - kd * 9, kh = r2 / 3, kw = r2 - kh * 3;
    const char* abase = ibz + ((kd * PD + kh) * PD + kw) * ROWBF + h * ROWB;   // SALU
    #pragma unroll
    for (int i = 0; i < A_IW; i++)
      gload16(abase + a_off[i], &As[buf][(wave * A_IW + i) * 1024]);
    const char* bbase = wb + (size_t)k * COUT * ROWBF + h * ROWB;              // SALU
    #pragma unroll
    for (int i = 0; i < B_IW; i++)
      gload16(bbase + b_off[i], &Bs[buf][(wave * B_IW + i) * 1024]);
  };

  f32x4 acc[MF][NF] = {};
  const int ll = lane & 15, lh = lane >> 4;
  const int ra0 = wm * MF * 16 + ll;
  const int rb0 = wn * NF * 16 + ll;
  const int rswa = key(ra0);
  const int rswb = key(rb0);

  stage(0, 0);
  __syncthreads();
  int cur = 0;
  for (int s = 0; s < NSTEP; s++) {
    if (s < NSTEP - 1) stage(cur ^ 1, s + 1);
    #pragma unroll
    for (int c = 0; c < CI0S; c++) {
      const int q = c * 4 + lh;
      half8 a[MF], bb[NF];
      #pragma unroll
      for (int mf = 0; mf < MF; mf++)
        a[mf] = *reinterpret_cast<const half8*>(
            &As[cur][(ra0 + mf * 16) * ROWB + ((q ^ rswa) * 16)]);
      #pragma unroll
      for (int nf = 0; nf < NF; nf++)
        bb[nf] = *reinterpret_cast<const half8*>(
            &Bs[cur][(rb0 + nf * 16) * ROWB + ((q ^ rswb) * 16)]);
      #pragma unroll
      for (int mf = 0; mf < MF; mf++)
        #pragma unroll
        for (int nf = 0; nf < NF; nf++)
          acc[mf][nf] = __builtin_amdgcn_mfma_f32_16x16x32_f16(a[mf], bb[nf], acc[mf][nf], 0, 0, 0);
    }
    __syncthreads();
    cur ^= 1;
  }

  f16* ob = out;
  float bv[NF];
  #pragma unroll
  for (int nf = 0; nf < NF; nf++) bv[nf] = bias[co0 + wn * NF * 16 + nf * 16 + ll];
  float pmax[NF];
  #pragma unroll
  for (int nf = 0; nf < NF; nf++) pmax[nf] = 0.f;
  #pragma unroll
  for (int mf = 0; mf < MF; mf++) {
    #pragma unroll
    for (int r = 0; r < 4; r++) {
      int v = v0 + wm * MF * 16 + mf * 16 + (lh << 2) + r;
      int vb = BMERGE ? (v >> (3 * LOGD)) : bz;
      int vv = BMERGE ? (v & (D3o - 1)) : v;
      bool act = mo[(size_t)vb * D3o + vv] != 0;
      int ow = vv & (DOUT - 1), oh = (vv >> LOGD) & (DOUT - 1), od = vv >> (2 * LOGD);
      size_t pv = OP ? (((size_t)(od + 1) * PDo + oh + 1) * PDo + ow + 1) : (size_t)vv;
      size_t obase = ((size_t)vb * (OP ? PDo * PDo * PDo : D3o) + pv) * COUT;
      #pragma unroll
      for (int nf = 0; nf < NF; nf++) {
        int co = co0 + wn * NF * 16 + nf * 16 + ll;
        float val = acc[mf][nf][r] + bv[nf];
        val = act ? (val > 0.f ? val : 0.f) : 0.f;
        if constexpr (POOL) {
          pmax[nf] = fmaxf(pmax[nf], val);
        } else {
          ob[obase + co] = (f16)val;
        }
      }
    }
  }
  if constexpr (POOL) {
    #pragma unroll
    for (int nf = 0; nf < NF; nf++) {
      int co = co0 + wn * NF * 16 + nf * 16 + ll;
      atomicMax((int*)poolp + bz * 512 + co, __float_as_int(pmax[nf]));
    }
  }
}

extern "C" void kernel_launch(void* const* d_in, const int* in_sizes, int n_in,
                              void* d_out, int out_size, void* d_ws, size_t ws_size,
                              hipStream_t stream) {
  const float* x    = (const float*)d_in[0];
  const int*   mask = (const int*)d_in[1];
  const float* w1 = (const float*)d_in[2];
  const float* b1 = (const float*)d_in[3];
  const float* w2 = (const float*)d_in[4];
  const float* b2 = (const float*)d_in[5];
  const float* w3 = (const float*)d_in[6];
  const float* b3 = (const float*)d_in[7];
  const float* w4 = (const float*)d_in[8];
  const float* b4 = (const float*)d_in[9];
  float* outp = (float*)d_out;

  const size_t PD1 = 66 * 66 * 66;   // 287496
  const size_t PD2 = 34 * 34 * 34;   // 39304
  const size_t PD3s = 18 * 18 * 18;  // 5832

  char* ws = (char*)d_ws;
  size_t off = 0;
  auto alloc = [&](size_t bytes) -> char* {
    char* p = ws + off;
    off = (off + bytes + 255) & ~(size_t)255;
    return p;
  };
  f16* wf1 = (f16*)alloc((size_t)64 * 128 * 2);
  f16* wf2 = (f16*)alloc((size_t)27 * 128 * 64 * 2);
  f16* wf3 = (f16*)alloc((size_t)27 * 256 * 128 * 2);
  f16* wf4 = (f16*)alloc((size_t)27 * 512 * 256 * 2);
  unsigned char* aw = (unsigned char*)alloc((size_t)BATCH * 262144);
  unsigned char* m1 = (unsigned char*)alloc((size_t)BATCH * 262144);
  unsigned char* m2 = (unsigned char*)alloc((size_t)BATCH * 32768);
  unsigned char* m3 = (unsigned char*)alloc((size_t)BATCH * 4096);
  unsigned char* m4 = (unsigned char*)alloc((size_t)BATCH * 512);
  f16* h1p = (f16*)alloc((size_t)BATCH * PD1 * 64 * 2);    // 147 MB
  f16* h2p = (f16*)alloc((size_t)BATCH * PD2 * 128 * 2);   // 40 MB
  f16* h3p = (f16*)alloc((size_t)BATCH * PD3s * 256 * 2);  // 12 MB
  f16* xcp = (f16*)alloc((size_t)BATCH * PD1 * 4 * 2);     // 9.2 MB
  if (off > ws_size) return;

  // merged weight prep (1 launch)
  {
    const int TOT = 64 * 128 + 27 * 128 * 64 + 27 * 256 * 128 + 27 * 512 * 256;
    wprep_all_k<<<dim3((TOT + 255) / 256), 256, 0, stream>>>(w1, w2, w3, w4, wf1, wf2, wf3, wf4);
  }

  // mask pyramid
  dil_w_k<<<dim3(BATCH * 65536 / 256), 256, 0, stream>>>(mask, aw);
  dil_hd2_k<<<dim3(BATCH * 65536 / 256), 256, 0, stream>>>(aw, m1);
  {
    const int TOT = BATCH * 32768 + BATCH * 4096 + BATCH * 512 + 2048;
    dil_rest_k<<<dim3((TOT + 255) / 256), 256, 0, stream>>>(m1, m2, m3, m4, outp);
  }

  // merged prep: xcp fill + h1p/h2p/h3p border zero (1 launch)
  {
    const int TOT = 287496 * 2 + 39304 + 5832;
    prep_all_k<<<dim3((TOT + 255) / 256, BATCH), 256, 0, stream>>>(
        x, mask, xcp, (char*)h1p, (char*)h2p, (char*)h3p);
  }

  // conv1 (halo-tile staging)
  conv1_mfma_k<128><<<dim3(262144 / 128, BATCH), 256, 0, stream>>>(xcp, wf1, b1, m1, h1p);

  // conv2: CINS64, BM64 BN128 MF2xNF4, 48KB LDS -> 3 blocks/CU, grid 512x1x4, SWZ
  conv_mfma2_k<64, 64, 128, 64, 32, 64, 128, 2, 2, 1, 1, 0, 0>
      <<<dim3(512, 1, BATCH), 256, 0, stream>>>(h1p, wf2, b2, m2, h2p, nullptr);
  // conv3: batch-merged M=16384, CINS64 ci-split2, BM64 BN128, 48KB, grid 256x2, SWZ
  conv_mfma2_k<64, 128, 256, 32, 16, 64, 128, 2, 2, 1, 1, 1, 0>
      <<<dim3(256, 2, 1), 256, 0, stream>>>(h2p, wf3, b3, m3, h3p, nullptr);
  // conv4: CINS128 ci-split2, BM32 BN64, 2 waves, 48KB, grid 16x8x4 — POOL fused (atomicMax)
  conv_mfma2_k<128, 256, 512, 16, 8, 32, 64, 1, 2, 0, 0, 0, 1>
      <<<dim3(16, 8, BATCH), 128, 0, stream>>>(h3p, wf4, b4, m4, nullptr, outp);
}